// Round 17
// baseline (209.798 us; speedup 1.0000x reference)
//
#include <hip/hip_runtime.h>

typedef __attribute__((ext_vector_type(4))) float f32x4;
typedef __attribute__((ext_vector_type(8))) short bf16x8;

#define GVOID const __attribute__((address_space(1))) void
#define LVOID __attribute__((address_space(3))) void

#define LOG2E 1.44269504f
#define LN2   0.69314718f

__device__ __forceinline__ float bf2f(ushort u){
  union { float f; unsigned int i; } c; c.i = ((unsigned int)u) << 16; return c.f;
}
__device__ __forceinline__ ushort f2bf(float f){
  union { float f; unsigned int i; } c; c.f = f;
  unsigned int r = (c.i + 0x7FFFu + ((c.i >> 16) & 1u)) >> 16;
  return (ushort)r;
}

// ---------------- fused f32 -> bf16 convert (all 9 tensors, one dispatch) ----------------
struct CvtArgs {
  const float* s[9];
  ushort*      d[9];
  int          blks[9];
};
__global__ __launch_bounds__(256) void cvtk_multi(CvtArgs ca){
  int bid = blockIdx.x;
  int seg = 0, base = 0;
  while (bid - base >= ca.blks[seg]){ base += ca.blks[seg]; ++seg; }
  int i = ((bid - base) * 256 + threadIdx.x) * 4;
  float4 v = *(const float4*)(ca.s[seg] + i);
  ushort4 o;
  o.x = f2bf(v.x); o.y = f2bf(v.y); o.z = f2bf(v.z); o.w = f2bf(v.w);
  *(ushort4*)(ca.d[seg] + i) = o;
}

// ---------------- GEMM args ----------------
struct GemmArgs {
  const ushort* A[3];
  const ushort* W[3];
  const float*  bias[3];
  const ushort* R[3];
  ushort*       C[3];
  int           mode[3];
  float         scale[3];
};

// ---------------- GEMM 128x128 (m97 structure): single-buffered, 2 barriers/K-step ----------------
__global__ __launch_bounds__(256,3) void gemm128(GemmArgs ga, int nmat, int N, int K){
  __shared__ ushort As[128 * 64];
  __shared__ ushort Bs[128 * 64];
  const int ntn = N >> 7;
  const int per = ntn * nmat;
  const int x = blockIdx.x & 7, ii = blockIdx.x >> 3;
  const int ipx = gridDim.x >> 3;
  const int gpx = ipx / per;
  const int tm = x * gpx + ii / per;
  const int q = ii % per;
  const int g = q / ntn, tn = q % ntn;
  const ushort* __restrict__ A = ga.A[g];
  const ushort* __restrict__ W = ga.W[g];
  const float*  __restrict__ bias = ga.bias[g];
  ushort* __restrict__ C = ga.C[g];
  const int mode = ga.mode[g];
  const float scale = ga.scale[g];

  const int t = threadIdx.x, lane = t & 63, wave = t >> 6;
  const int wr = wave >> 1, wc = wave & 1;
  const int l15 = lane & 15, l4 = lane >> 4;
  const int rowBase = tm * 128, colBase = tn * 128;

  f32x4 acc[4][4] = {};
  const int NT = K >> 6;
  for (int tk = 0; tk < NT; ++tk){
    const int k0 = tk * 64;
    __syncthreads();
#pragma unroll
    for (int j = 0; j < 4; ++j){
      int cb = j * 256 + wave * 64 + lane;
      int row = cb >> 3;
      int kc = (cb & 7) ^ (row & 7);
      const ushort* srcA = A + (size_t)(rowBase + row) * K + k0 + kc * 8;
      __builtin_amdgcn_global_load_lds((GVOID*)srcA, (LVOID*)(As + (size_t)cb * 8), 16, 0, 0);
      const ushort* srcB = W + (size_t)(colBase + row) * K + k0 + kc * 8;
      __builtin_amdgcn_global_load_lds((GVOID*)srcB, (LVOID*)(Bs + (size_t)cb * 8), 16, 0, 0);
    }
    __syncthreads();
#pragma unroll
    for (int kk = 0; kk < 2; ++kk){
      bf16x8 a[4], b[4];
#pragma unroll
      for (int m = 0; m < 4; ++m){
        int row = wr * 64 + m * 16 + l15;
        int ch = row * 8 + ((kk * 4 + l4) ^ (row & 7));
        a[m] = *(const bf16x8*)(As + ch * 8);
      }
#pragma unroll
      for (int n = 0; n < 4; ++n){
        int row = wc * 64 + n * 16 + l15;
        int ch = row * 8 + ((kk * 4 + l4) ^ (row & 7));
        b[n] = *(const bf16x8*)(Bs + ch * 8);
      }
#pragma unroll
      for (int m = 0; m < 4; ++m)
#pragma unroll
      for (int n = 0; n < 4; ++n)
        acc[m][n] = __builtin_amdgcn_mfma_f32_16x16x32_bf16(a[m], b[n], acc[m][n], 0, 0, 0);
    }
  }
#pragma unroll
  for (int m = 0; m < 4; ++m)
#pragma unroll
  for (int n = 0; n < 4; ++n)
#pragma unroll
  for (int r = 0; r < 4; ++r){
    int row = rowBase + wr * 64 + m * 16 + l4 * 4 + r;
    int col = colBase + wc * 64 + n * 16 + l15;
    float v = (acc[m][n][r] + bias[col]) * scale;
    if (mode == 2){
      int bb = row >> 10, tt = row & 1023, nh = col >> 6, d = col & 63;
      C[((size_t)((bb * 16 + nh) * 64 + d)) * 1024 + tt] = f2bf(v);
    } else {
      C[(size_t)row * N + col] = f2bf(v);
    }
  }
}

// ---------------- GEMM 128x64 double-buffered, counted-vmcnt (T4) ----------------
// Per iter: stage(T+1) [6 loads] ; vmcnt(6)+bar (buf T landed, T+1 in flight) ;
// compute ; lgkmcnt(0)+bar (WAR). No full drain in the loop.
__global__ __launch_bounds__(256,3) void gemm_bt(GemmArgs ga, int nmat, int M, int N, int K){
  __shared__ ushort As[2][128 * 64];
  __shared__ ushort Bs[2][64 * 64];
  const int nb = gridDim.x;
  const int ntn = N >> 6;
  const int tq_cnt = ntn * nmat;
  const int x = blockIdx.x & 7, ii = blockIdx.x >> 3;
  const int ipx = nb >> 3;
  const int gpx = ipx / tq_cnt;
  const int tm = x * gpx + ii / tq_cnt;
  const int tq = ii % tq_cnt;
  const int g = tq / ntn, tn = tq % ntn;
  const ushort* __restrict__ A = ga.A[g];
  const ushort* __restrict__ W = ga.W[g];
  const float*  __restrict__ bias = ga.bias[g];
  const ushort* __restrict__ R = ga.R[g];
  ushort* __restrict__ C = ga.C[g];
  const int mode = ga.mode[g];
  const float scale = ga.scale[g];

  const int t = threadIdx.x, lane = t & 63, wave = t >> 6;
  const int wr = wave >> 1, wc = wave & 1;
  const int l15 = lane & 15, l4 = lane >> 4;
  const int rowBase = tm * 128, colBase = tn * 64;

  auto stage = [&](int buf, int k0){
#pragma unroll
    for (int j = 0; j < 4; ++j){
      int cb = j * 256 + wave * 64;
      int p = cb + lane;
      int row = p >> 3;
      int kc = (p & 7) ^ (row & 7);
      const ushort* src = A + (size_t)(rowBase + row) * K + k0 + kc * 8;
      __builtin_amdgcn_global_load_lds((GVOID*)src, (LVOID*)(&As[buf][cb * 8]), 16, 0, 0);
    }
#pragma unroll
    for (int j = 0; j < 2; ++j){
      int cb = j * 256 + wave * 64;
      int p = cb + lane;
      int row = p >> 3;
      int kc = (p & 7) ^ (row & 7);
      const ushort* src = W + (size_t)(colBase + row) * K + k0 + kc * 8;
      __builtin_amdgcn_global_load_lds((GVOID*)src, (LVOID*)(&Bs[buf][cb * 8]), 16, 0, 0);
    }
  };

  f32x4 acc[4][2] = {};
  const int NT = K >> 6;
  stage(0, 0);                                   // 6 outstanding
  for (int tk = 0; tk < NT; ++tk){
    const int cur = tk & 1;
    if (tk + 1 < NT){
      stage(cur ^ 1, (tk + 1) * 64);             // 12 outstanding
      asm volatile("s_waitcnt vmcnt(6)" ::: "memory");   // buf cur landed; next in flight
    } else {
      asm volatile("s_waitcnt vmcnt(0)" ::: "memory");
    }
    __builtin_amdgcn_s_barrier();
#pragma unroll
    for (int kk = 0; kk < 2; ++kk){
      bf16x8 a[4], b[2];
#pragma unroll
      for (int m = 0; m < 4; ++m){
        int row = wr * 64 + m * 16 + l15;
        int ch = row * 8 + kk * 4 + l4;
        ch ^= (row & 7);
        a[m] = *(const bf16x8*)(&As[cur][ch * 8]);
      }
#pragma unroll
      for (int n = 0; n < 2; ++n){
        int row = wc * 32 + n * 16 + l15;
        int ch = row * 8 + kk * 4 + l4;
        ch ^= (row & 7);
        b[n] = *(const bf16x8*)(&Bs[cur][ch * 8]);
      }
#pragma unroll
      for (int m = 0; m < 4; ++m)
#pragma unroll
      for (int n = 0; n < 2; ++n)
        acc[m][n] = __builtin_amdgcn_mfma_f32_16x16x32_bf16(a[m], b[n], acc[m][n], 0, 0, 0);
    }
    asm volatile("s_waitcnt lgkmcnt(0)" ::: "memory");   // reads done before buf reuse
    __builtin_amdgcn_s_barrier();
  }
#pragma unroll
  for (int m = 0; m < 4; ++m)
#pragma unroll
  for (int n = 0; n < 2; ++n)
#pragma unroll
  for (int r = 0; r < 4; ++r){
    int row = rowBase + wr * 64 + m * 16 + l4 * 4 + r;
    int col = colBase + wc * 32 + n * 16 + l15;
    float v = (acc[m][n][r] + bias[col]) * scale;
    if (mode == 1) v += bf2f(R[(size_t)row * N + col]) * LN2;   // residual stored pre-scaled by LOG2E
    C[(size_t)row * N + col] = f2bf(v);
  }
}

// ---------------- fused flash attention v9 (counted-vmcnt pipeline) ----------------
// 1024 blocks (b, head, 16 q-tiles of 64), 4 waves x 16 q-rows. LDS 32 KB -> 4 blocks/CU.
// Per iter: issue V(kt)[4] + K(kt+1)[4]; vmcnt(8)+bar pre-QK^T (K(kt) landed, prefetch alive);
// vmcnt(4)+bar pre-PV (V landed, K(kt+1) alive); end bar (WAR). No full drain in the loop.
__global__ __launch_bounds__(256,4) void attn_kernel(const ushort* __restrict__ Q, const ushort* __restrict__ Kv,
    const ushort* __restrict__ Vt, ushort* __restrict__ O, const int* __restrict__ smask, int causal){
  __shared__ ushort Ks[2][64 * 64];           // 16 KB (double-buffered)
  __shared__ ushort Vs[64 * 64];              // 8 KB (single-buffered)
  __shared__ __align__(16) char Ps[4][2048];  // 8 KB
  const int p = blockIdx.x;
  const int x = p & 7, j = p >> 3;          // XCD, local 0..127
  const int gg = x * 8 + (j & 7);           // (b,head), co-located per XCD
  const int b = gg >> 4, head = gg & 15;
  const int rr = j >> 3;                    // 0..15
  int qt;
  if (causal){
    int lo = rr & 3, hi = rr >> 2;          // stride-4 class balance
    qt = (hi == 0) ? lo * 2 : (hi == 1) ? lo * 2 + 1 : (hi == 2) ? 15 - lo * 2 : 14 - lo * 2;
  } else qt = rr;
  const int t = threadIdx.x, lane = t & 63, wave = t >> 6;
  const int l15 = lane & 15, l4 = lane >> 4;
  const int qr0 = qt * 64 + wave * 16;
  const int sw = l15 << 3;                  // 4-bit slot swizzle: bijective, conflict-free b64

  bf16x8 aq[2];
#pragma unroll
  for (int kk = 0; kk < 2; ++kk)
    aq[kk] = *(const bf16x8*)(Q + (size_t)(b * 1024 + qr0 + l15) * 1024 + head * 64 + kk * 32 + l4 * 8);

  f32x4 cacc[4] = {};
  float mrow = -1e30f, lrow = 0.f;

  auto stageK = [&](int buf, int k0){
#pragma unroll
    for (int jj = 0; jj < 2; ++jj){
      int cb = jj * 256 + wave * 64;
      int pp = cb + lane;
      int row = pp >> 3;
      int kc = (pp & 7) ^ (row & 7);
      const ushort* src = Kv + (size_t)(b * 1024 + k0 + row) * 1024 + head * 64 + kc * 8;
      __builtin_amdgcn_global_load_lds((GVOID*)src, (LVOID*)(&Ks[buf][cb * 8]), 16, 0, 0);
    }
  };
  auto stageV = [&](int k0){
#pragma unroll
    for (int jj = 0; jj < 2; ++jj){
      int cb = jj * 256 + wave * 64;
      int pp = cb + lane;
      int row = pp >> 3;
      int kc = (pp & 7) ^ (row & 7);
      const ushort* src = Vt + (size_t)((b * 16 + head) * 64 + row) * 1024 + k0 + kc * 8;
      __builtin_amdgcn_global_load_lds((GVOID*)src, (LVOID*)(Vs + cb * 8), 16, 0, 0);
    }
  };

  const int nkt = causal ? (qt + 1) : 16;
  stageK(0, 0);                               // 4 outstanding (K(0))
  char* Pb = &Ps[wave][0];
  for (int kt = 0; kt < nkt; ++kt){
    const int cur = kt & 1;
    const int k0 = kt * 64;
    const bool pk = (kt + 1 < nkt);
    stageV(k0);                               // +4
    if (pk) stageK(cur ^ 1, (kt + 1) * 64);   // +4
    // K(kt) landed (issued last iteration); V + K(kt+1) stay in flight
    if (pk) asm volatile("s_waitcnt vmcnt(8)" ::: "memory");
    else    asm volatile("s_waitcnt vmcnt(4)" ::: "memory");
    __builtin_amdgcn_s_barrier();
    const ushort* Kb_ = &Ks[cur][0];
    f32x4 st[4] = {};
#pragma unroll
    for (int kk = 0; kk < 2; ++kk){
      bf16x8 ak[4];
#pragma unroll
      for (int n = 0; n < 4; ++n){
        int row = n * 16 + l15;
        int ch = row * 8 + ((kk * 4 + l4) ^ (row & 7));
        ak[n] = *(const bf16x8*)(Kb_ + ch * 8);
      }
#pragma unroll
      for (int n = 0; n < 4; ++n)
        st[n] = __builtin_amdgcn_mfma_f32_16x16x32_bf16(ak[n], aq[kk], st[n], 0, 0, 0);
    }
    if (causal && k0 + 63 > qr0){
#pragma unroll
      for (int n = 0; n < 4; ++n)
#pragma unroll
      for (int r = 0; r < 4; ++r)
        if (k0 + n * 16 + l4 * 4 + r > qr0 + l15) st[n][r] = -1.5e6f;
    }
    if (smask){
      int myv = smask[b * 1024 + k0 + lane];          // one coalesced load per wave (scalar-cached)
      if (!__all(myv != 0)){
#pragma unroll
        for (int n = 0; n < 4; ++n)
#pragma unroll
        for (int r = 0; r < 4; ++r){
          int mv = smask[b * 1024 + k0 + n * 16 + l4 * 4 + r];
          if (mv == 0) st[n][r] = -1.5e6f;
        }
      }
    }
    float mx = st[0][0];
#pragma unroll
    for (int n = 0; n < 4; ++n)
#pragma unroll
    for (int r = 0; r < 4; ++r) mx = fmaxf(mx, st[n][r]);
    mx = fmaxf(mx, __shfl_xor(mx, 16));
    mx = fmaxf(mx, __shfl_xor(mx, 32));
    if (!__all(mx <= mrow + 8.f)){
      float mn = fmaxf(mrow, mx);
      float scal = __builtin_amdgcn_exp2f(mrow - mn);
      mrow = mn;
      lrow *= scal;
#pragma unroll
      for (int r = 0; r < 4; ++r){
        float sb = __shfl(scal, l4 * 4 + r);
#pragma unroll
        for (int nd = 0; nd < 4; ++nd) cacc[nd][r] *= sb;
      }
    }
    float ps = 0.f;
#pragma unroll
    for (int n = 0; n < 4; ++n)
#pragma unroll
    for (int r = 0; r < 4; ++r){
      float pv = __builtin_amdgcn_exp2f(st[n][r] - mrow);
      st[n][r] = pv;
      ps += pv;
    }
    ps += __shfl_xor(ps, 16);
    ps += __shfl_xor(ps, 32);
    lrow += ps;
#pragma unroll
    for (int n = 0; n < 4; ++n){
      unsigned lo_, hi_;
      asm("v_cvt_pk_bf16_f32 %0, %1, %2" : "=v"(lo_) : "v"(st[n][0]), "v"(st[n][1]));
      asm("v_cvt_pk_bf16_f32 %0, %1, %2" : "=v"(hi_) : "v"(st[n][2]), "v"(st[n][3]));
      unsigned long long pk2 = (unsigned long long)lo_ | ((unsigned long long)hi_ << 32);
      *(unsigned long long*)(Pb + l15 * 128 + ((n * 32 + l4 * 8) ^ sw)) = pk2;
    }
    // V(kt) landed, visible to all waves; K(kt+1) stays in flight
    if (pk) asm volatile("s_waitcnt vmcnt(4)" ::: "memory");
    else    asm volatile("s_waitcnt vmcnt(0)" ::: "memory");
    __builtin_amdgcn_s_barrier();
#pragma unroll
    for (int ks = 0; ks < 2; ++ks){
      bf16x8 bv[4];
#pragma unroll
      for (int nd = 0; nd < 4; ++nd){
        int row = nd * 16 + l15;
        int ch = row * 8 + ((ks * 4 + l4) ^ (row & 7));
        bv[nd] = *(const bf16x8*)(Vs + ch * 8);
      }
      int base = l15 * 128;
      int o = ks * 64 + l4 * 16;
      union { bf16x8 v; unsigned long long u[2]; } pa;
      pa.u[0] = *(const unsigned long long*)(Pb + base + ((o    ) ^ sw));
      pa.u[1] = *(const unsigned long long*)(Pb + base + ((o + 8) ^ sw));
#pragma unroll
      for (int nd = 0; nd < 4; ++nd)
        cacc[nd] = __builtin_amdgcn_mfma_f32_16x16x32_bf16(pa.v, bv[nd], cacc[nd], 0, 0, 0);
    }
    asm volatile("s_waitcnt lgkmcnt(0)" ::: "memory");   // Vs/Ks reads done
    __builtin_amdgcn_s_barrier();                        // before next-iter overwrite
  }
#pragma unroll
  for (int r = 0; r < 4; ++r){
    float lb = __shfl(lrow, l4 * 4 + r);
    float inv = 1.f / lb;
    int row = qr0 + l4 * 4 + r;
#pragma unroll
    for (int nd = 0; nd < 4; ++nd){
      int col = head * 64 + nd * 16 + l15;
      O[(size_t)(b * 1024 + row) * 1024 + col] = f2bf(cacc[nd][r] * inv);
    }
  }
}

// ---------------- LayerNorm over H=1024 ----------------
__global__ __launch_bounds__(256) void ln_kernel(const ushort* __restrict__ X, const float* __restrict__ g,
    const float* __restrict__ bta, ushort* __restrict__ outb, float* __restrict__ outf){
  const int row = blockIdx.x, t = threadIdx.x;
  const ushort* xr = X + (size_t)row * 1024;
  ushort4 u = *(const ushort4*)(xr + t * 4);
  float x0 = bf2f(u.x), x1 = bf2f(u.y), x2 = bf2f(u.z), x3 = bf2f(u.w);
  float s = x0 + x1 + x2 + x3;
  float s2 = x0 * x0 + x1 * x1 + x2 * x2 + x3 * x3;
#pragma unroll
  for (int d = 1; d < 64; d <<= 1){ s += __shfl_xor(s, d); s2 += __shfl_xor(s2, d); }
  __shared__ float red[8];
  const int lane = t & 63, wave = t >> 6;
  if (lane == 0){ red[wave] = s; red[4 + wave] = s2; }
  __syncthreads();
  s = red[0] + red[1] + red[2] + red[3];
  s2 = red[4] + red[5] + red[6] + red[7];
  float mu = s * (1.f / 1024.f);
  float var = fmaxf(s2 * (1.f / 1024.f) - mu * mu, 0.f);
  float rstd = rsqrtf(var + 1e-12f);
  int col = t * 4;
  float y0 = (x0 - mu) * rstd * g[col + 0] + bta[col + 0];
  float y1 = (x1 - mu) * rstd * g[col + 1] + bta[col + 1];
  float y2 = (x2 - mu) * rstd * g[col + 2] + bta[col + 2];
  float y3 = (x3 - mu) * rstd * g[col + 3] + bta[col + 3];
  if (outb){
    ushort4 o; o.x = f2bf(y0); o.y = f2bf(y1); o.z = f2bf(y2); o.w = f2bf(y3);
    *(ushort4*)(outb + (size_t)row * 1024 + col) = o;
  } else {
    float4 o; o.x = y0; o.y = y1; o.z = y2; o.w = y3;
    *(float4*)(outf + (size_t)row * 1024 + col) = o;
  }
}

extern "C" void kernel_launch(void* const* d_in, const int* in_sizes, int n_in,
                              void* d_out, int out_size, void* d_ws, size_t ws_size,
                              hipStream_t stream){
  const float* enc = (const float*)d_in[0];
  const float* dec = (const float*)d_in[1];
  const int* smask = (const int*)d_in[2];
  const float* q_w  = (const float*)d_in[4];  const float* q_b  = (const float*)d_in[5];
  const float* k_w  = (const float*)d_in[6];  const float* k_b  = (const float*)d_in[7];
  const float* v_w  = (const float*)d_in[8];  const float* v_b  = (const float*)d_in[9];
  const float* sq_w = (const float*)d_in[10]; const float* sq_b = (const float*)d_in[11];
  const float* sk_w = (const float*)d_in[12]; const float* sk_b = (const float*)d_in[13];
  const float* sv_w = (const float*)d_in[14]; const float* sv_b = (const float*)d_in[15];
  const float* dw   = (const float*)d_in[16]; const float* db   = (const float*)d_in[17];
  const float* lng  = (const float*)d_in[18]; const float* lnb  = (const float*)d_in[19];
  ushort* ws = (ushort*)d_ws;
  const size_t MEG = 1024u * 1024u;
  ushort* decb = ws + 0 * MEG;
  ushort* encb = ws + 4 * MEG;
  ushort* Qb   = ws + 8 * MEG;
  ushort* Kb   = ws + 12 * MEG;
  ushort* Vtb  = ws + 20 * MEG;
  ushort* ctx  = ws + 24 * MEG;
  ushort* S1   = ws + 28 * MEG;
  ushort* Wq  = ws + 32 * MEG; ushort* Wk  = ws + 33 * MEG; ushort* Wv  = ws + 34 * MEG;
  ushort* Wsq = ws + 35 * MEG; ushort* Wsk = ws + 36 * MEG; ushort* Wsv = ws + 37 * MEG;
  ushort* Wd  = ws + 38 * MEG;
  const int M = 4096, N = 1024, Kd = 1024;
  {
    CvtArgs ca;
    ca.s[0] = dec;  ca.d[0] = decb; ca.blks[0] = 4096;
    ca.s[1] = enc;  ca.d[1] = encb; ca.blks[1] = 4096;
    ca.s[2] = q_w;  ca.d[2] = Wq;   ca.blks[2] = 1024;
    ca.s[3] = k_w;  ca.d[3] = Wk;   ca.blks[3] = 1024;
    ca.s[4] = v_w;  ca.d[4] = Wv;   ca.blks[4] = 1024;
    ca.s[5] = sq_w; ca.d[5] = Wsq;  ca.blks[5] = 1024;
    ca.s[6] = sk_w; ca.d[6] = Wsk;  ca.blks[6] = 1024;
    ca.s[7] = sv_w; ca.d[7] = Wsv;  ca.blks[7] = 1024;
    ca.s[8] = dw;   ca.d[8] = Wd;   ca.blks[8] = 1024;
    cvtk_multi<<<15360, 256, 0, stream>>>(ca);
  }
  // ---- self attention ----
  {
    GemmArgs ga = {};
    ga.A[0] = decb; ga.A[1] = decb; ga.A[2] = decb;
    ga.W[0] = Wq;   ga.W[1] = Wk;   ga.W[2] = Wv;
    ga.bias[0] = q_b; ga.bias[1] = k_b; ga.bias[2] = v_b;
    ga.C[0] = Qb;   ga.C[1] = Kb;   ga.C[2] = Vtb;
    ga.mode[0] = 0; ga.mode[1] = 0; ga.mode[2] = 2;
    ga.scale[0] = LOG2E; ga.scale[1] = 1.f; ga.scale[2] = 1.f;
    gemm128<<<768, 256, 0, stream>>>(ga, 3, N, Kd);
  }
  attn_kernel<<<1024, 256, 0, stream>>>(Qb, Kb, Vtb, ctx, nullptr, 1);
  {
    GemmArgs ga = {};
    ga.A[0] = ctx; ga.W[0] = Wd; ga.bias[0] = db; ga.R[0] = Qb; ga.C[0] = S1; ga.mode[0] = 1;
    ga.scale[0] = 1.f;
    gemm_bt<<<512, 256, 0, stream>>>(ga, 1, M, N, Kd);
  }
  ln_kernel<<<4096, 256, 0, stream>>>(S1, lng, lnb, decb, nullptr);
  // ---- cross attention ----
  {
    GemmArgs ga = {};
    ga.A[0] = decb; ga.A[1] = encb; ga.A[2] = encb;
    ga.W[0] = Wsq;  ga.W[1] = Wsk;  ga.W[2] = Wsv;
    ga.bias[0] = sq_b; ga.bias[1] = sk_b; ga.bias[2] = sv_b;
    ga.C[0] = Qb;   ga.C[1] = Kb;   ga.C[2] = Vtb;
    ga.mode[0] = 0; ga.mode[1] = 0; ga.mode[2] = 2;
    ga.scale[0] = LOG2E; ga.scale[1] = 1.f; ga.scale[2] = 1.f;
    gemm128<<<768, 256, 0, stream>>>(ga, 3, N, Kd);
  }
  attn_kernel<<<1024, 256, 0, stream>>>(Qb, Kb, Vtb, ctx, smask, 0);
  {
    GemmArgs ga = {};
    ga.A[0] = ctx; ga.W[0] = Wd; ga.bias[0] = db; ga.R[0] = Qb; ga.C[0] = S1; ga.mode[0] = 1;
    ga.scale[0] = 1.f;
    gemm_bt<<<512, 256, 0, stream>>>(ga, 1, M, N, Kd);
  }
  ln_kernel<<<4096, 256, 0, stream>>>(S1, lng, lnb, nullptr, (float*)d_out);
}

// Round 18
// 193.228 us; speedup vs baseline: 1.0858x; 1.0858x over previous
//
#include <hip/hip_runtime.h>

typedef __attribute__((ext_vector_type(4))) float f32x4;
typedef __attribute__((ext_vector_type(8))) short bf16x8;

#define GVOID const __attribute__((address_space(1))) void
#define LVOID __attribute__((address_space(3))) void

#define LOG2E 1.44269504f
#define LN2   0.69314718f

__device__ __forceinline__ float bf2f(ushort u){
  union { float f; unsigned int i; } c; c.i = ((unsigned int)u) << 16; return c.f;
}
__device__ __forceinline__ ushort f2bf(float f){
  union { float f; unsigned int i; } c; c.f = f;
  unsigned int r = (c.i + 0x7FFFu + ((c.i >> 16) & 1u)) >> 16;
  return (ushort)r;
}

// ---------------- fused f32 -> bf16 convert (all 9 tensors, one dispatch) ----------------
struct CvtArgs {
  const float* s[9];
  ushort*      d[9];
  int          blks[9];
};
__global__ __launch_bounds__(256) void cvtk_multi(CvtArgs ca){
  int bid = blockIdx.x;
  int seg = 0, base = 0;
  while (bid - base >= ca.blks[seg]){ base += ca.blks[seg]; ++seg; }
  int i = ((bid - base) * 256 + threadIdx.x) * 4;
  float4 v = *(const float4*)(ca.s[seg] + i);
  ushort4 o;
  o.x = f2bf(v.x); o.y = f2bf(v.y); o.z = f2bf(v.z); o.w = f2bf(v.w);
  *(ushort4*)(ca.d[seg] + i) = o;
}

// ---------------- GEMM args ----------------
struct GemmArgs {
  const ushort* A[3];
  const ushort* W[3];
  const float*  bias[3];
  const ushort* R[3];
  ushort*       C[3];
  int           mode[3];
  float         scale[3];
};

// ---------------- GEMM 128x128 (m97 structure): single-buffered, 2 barriers/K-step ----------------
// mode-2 epilogue: per-wave LDS transpose (8 KB quadrant) -> coalesced b128 stores.
__global__ __launch_bounds__(256,3) void gemm128(GemmArgs ga, int nmat, int N, int K){
  __shared__ ushort As[128 * 64];
  __shared__ ushort Bs[128 * 64];
  const int ntn = N >> 7;
  const int per = ntn * nmat;
  const int x = blockIdx.x & 7, ii = blockIdx.x >> 3;
  const int ipx = gridDim.x >> 3;
  const int gpx = ipx / per;
  const int tm = x * gpx + ii / per;
  const int q = ii % per;
  const int g = q / ntn, tn = q % ntn;
  const ushort* __restrict__ A = ga.A[g];
  const ushort* __restrict__ W = ga.W[g];
  const float*  __restrict__ bias = ga.bias[g];
  ushort* __restrict__ C = ga.C[g];
  const int mode = ga.mode[g];
  const float scale = ga.scale[g];

  const int t = threadIdx.x, lane = t & 63, wave = t >> 6;
  const int wr = wave >> 1, wc = wave & 1;
  const int l15 = lane & 15, l4 = lane >> 4;
  const int rowBase = tm * 128, colBase = tn * 128;

  f32x4 acc[4][4] = {};
  const int NT = K >> 6;
  for (int tk = 0; tk < NT; ++tk){
    const int k0 = tk * 64;
    __syncthreads();
#pragma unroll
    for (int j = 0; j < 4; ++j){
      int cb = j * 256 + wave * 64 + lane;
      int row = cb >> 3;
      int kc = (cb & 7) ^ (row & 7);
      const ushort* srcA = A + (size_t)(rowBase + row) * K + k0 + kc * 8;
      __builtin_amdgcn_global_load_lds((GVOID*)srcA, (LVOID*)(As + (size_t)cb * 8), 16, 0, 0);
      const ushort* srcB = W + (size_t)(colBase + row) * K + k0 + kc * 8;
      __builtin_amdgcn_global_load_lds((GVOID*)srcB, (LVOID*)(Bs + (size_t)cb * 8), 16, 0, 0);
    }
    __syncthreads();
#pragma unroll
    for (int kk = 0; kk < 2; ++kk){
      bf16x8 a[4], b[4];
#pragma unroll
      for (int m = 0; m < 4; ++m){
        int row = wr * 64 + m * 16 + l15;
        int ch = row * 8 + ((kk * 4 + l4) ^ (row & 7));
        a[m] = *(const bf16x8*)(As + ch * 8);
      }
#pragma unroll
      for (int n = 0; n < 4; ++n){
        int row = wc * 64 + n * 16 + l15;
        int ch = row * 8 + ((kk * 4 + l4) ^ (row & 7));
        b[n] = *(const bf16x8*)(Bs + ch * 8);
      }
#pragma unroll
      for (int m = 0; m < 4; ++m)
#pragma unroll
      for (int n = 0; n < 4; ++n)
        acc[m][n] = __builtin_amdgcn_mfma_f32_16x16x32_bf16(a[m], b[n], acc[m][n], 0, 0, 0);
    }
  }
  __syncthreads();                       // As/Bs dead: safe to reuse as epilogue scratch
  if (mode == 2){
    // per-wave private 8 KB quadrant of the 32 KB LDS pool
    ushort* scr = (wave < 2) ? (As + wave * 4096) : (Bs + (wave - 2) * 4096);
    // write wave's 64x64 tile transposed: [d_loc][t_loc], swizzle t ^= (d&7)<<3 (b64, 2-way free)
#pragma unroll
    for (int m = 0; m < 4; ++m)
#pragma unroll
    for (int n = 0; n < 4; ++n){
      int d_loc = n * 16 + l15;
      float bi = bias[colBase + wc * 64 + d_loc];
      float v0 = (acc[m][n][0] + bi) * scale;
      float v1 = (acc[m][n][1] + bi) * scale;
      float v2 = (acc[m][n][2] + bi) * scale;
      float v3 = (acc[m][n][3] + bi) * scale;
      unsigned lo_, hi_;
      asm("v_cvt_pk_bf16_f32 %0, %1, %2" : "=v"(lo_) : "v"(v0), "v"(v1));
      asm("v_cvt_pk_bf16_f32 %0, %1, %2" : "=v"(hi_) : "v"(v2), "v"(v3));
      unsigned long long pk = (unsigned long long)lo_ | ((unsigned long long)hi_ << 32);
      int t0 = m * 16 + l4 * 4;
      *(unsigned long long*)((char*)scr + d_loc * 128 + ((t0 ^ ((d_loc & 7) << 3)) * 2)) = pk;
    }
    // read back rows of d (same-wave RAW fenced by compiler lgkmcnt) -> coalesced 16B stores
    const int bb = rowBase >> 10;
    const int nh = (colBase + wc * 64) >> 6;
    const int ttBase = (rowBase & 1023) + wr * 64;
#pragma unroll
    for (int pz = 0; pz < 8; ++pz){
      int d_loc = pz * 8 + (lane >> 3);
      int t0 = (lane & 7) * 8;
      bf16x8 vv = *(const bf16x8*)((const char*)scr + d_loc * 128 + ((t0 ^ ((d_loc & 7) << 3)) * 2));
      *(bf16x8*)(C + ((size_t)((bb * 16 + nh) * 64 + d_loc)) * 1024 + ttBase + t0) = vv;
    }
  } else {
#pragma unroll
    for (int m = 0; m < 4; ++m)
#pragma unroll
    for (int n = 0; n < 4; ++n)
#pragma unroll
    for (int r = 0; r < 4; ++r){
      int row = rowBase + wr * 64 + m * 16 + l4 * 4 + r;
      int col = colBase + wc * 64 + n * 16 + l15;
      float v = (acc[m][n][r] + bias[col]) * scale;
      C[(size_t)row * N + col] = f2bf(v);
    }
  }
}

// ---------------- GEMM 128x64 double-buffered (dense projection, +unscaled residual) ----------------
__global__ __launch_bounds__(256,3) void gemm_bt(GemmArgs ga, int nmat, int M, int N, int K){
  __shared__ ushort As[2][128 * 64];
  __shared__ ushort Bs[2][64 * 64];
  const int nb = gridDim.x;
  const int ntn = N >> 6;
  const int tq_cnt = ntn * nmat;
  const int x = blockIdx.x & 7, ii = blockIdx.x >> 3;
  const int ipx = nb >> 3;
  const int gpx = ipx / tq_cnt;
  const int tm = x * gpx + ii / tq_cnt;
  const int tq = ii % tq_cnt;
  const int g = tq / ntn, tn = tq % ntn;
  const ushort* __restrict__ A = ga.A[g];
  const ushort* __restrict__ W = ga.W[g];
  const float*  __restrict__ bias = ga.bias[g];
  const ushort* __restrict__ R = ga.R[g];
  ushort* __restrict__ C = ga.C[g];
  const int mode = ga.mode[g];
  const float scale = ga.scale[g];

  const int t = threadIdx.x, lane = t & 63, wave = t >> 6;
  const int wr = wave >> 1, wc = wave & 1;
  const int l15 = lane & 15, l4 = lane >> 4;
  const int rowBase = tm * 128, colBase = tn * 64;

  auto stage = [&](int buf, int k0){
#pragma unroll
    for (int j = 0; j < 4; ++j){
      int cb = j * 256 + wave * 64;
      int p = cb + lane;
      int row = p >> 3;
      int kc = (p & 7) ^ (row & 7);
      const ushort* src = A + (size_t)(rowBase + row) * K + k0 + kc * 8;
      __builtin_amdgcn_global_load_lds((GVOID*)src, (LVOID*)(&As[buf][cb * 8]), 16, 0, 0);
    }
#pragma unroll
    for (int j = 0; j < 2; ++j){
      int cb = j * 256 + wave * 64;
      int p = cb + lane;
      int row = p >> 3;
      int kc = (p & 7) ^ (row & 7);
      const ushort* src = W + (size_t)(colBase + row) * K + k0 + kc * 8;
      __builtin_amdgcn_global_load_lds((GVOID*)src, (LVOID*)(&Bs[buf][cb * 8]), 16, 0, 0);
    }
  };

  f32x4 acc[4][2] = {};
  const int NT = K >> 6;
  stage(0, 0);
  __syncthreads();
  for (int tk = 0; tk < NT; ++tk){
    const int cur = tk & 1;
    if (tk + 1 < NT) stage(cur ^ 1, (tk + 1) * 64);
#pragma unroll
    for (int kk = 0; kk < 2; ++kk){
      bf16x8 a[4], b[2];
#pragma unroll
      for (int m = 0; m < 4; ++m){
        int row = wr * 64 + m * 16 + l15;
        int ch = row * 8 + kk * 4 + l4;
        ch ^= (row & 7);
        a[m] = *(const bf16x8*)(&As[cur][ch * 8]);
      }
#pragma unroll
      for (int n = 0; n < 2; ++n){
        int row = wc * 32 + n * 16 + l15;
        int ch = row * 8 + kk * 4 + l4;
        ch ^= (row & 7);
        b[n] = *(const bf16x8*)(&Bs[cur][ch * 8]);
      }
#pragma unroll
      for (int m = 0; m < 4; ++m)
#pragma unroll
      for (int n = 0; n < 2; ++n)
        acc[m][n] = __builtin_amdgcn_mfma_f32_16x16x32_bf16(a[m], b[n], acc[m][n], 0, 0, 0);
    }
    __syncthreads();
  }
#pragma unroll
  for (int m = 0; m < 4; ++m)
#pragma unroll
  for (int n = 0; n < 2; ++n)
#pragma unroll
  for (int r = 0; r < 4; ++r){
    int row = rowBase + wr * 64 + m * 16 + l4 * 4 + r;
    int col = colBase + wc * 32 + n * 16 + l15;
    float v = (acc[m][n][r] + bias[col]) * scale;
    if (mode == 1) v += bf2f(R[(size_t)row * N + col]) * LN2;   // residual stored pre-scaled by LOG2E
    C[(size_t)row * N + col] = f2bf(v);
  }
}

// ---------------- fused flash attention v5 (round-10/15 verified best) ----------------
// 1024 blocks (b, head, 16 q-tiles of 64), 4 waves x 16 q-rows, 4 blocks/CU.
// Swapped QK^T; Q pre-scaled by LOG2E (exp2 softmax); 4-bit P swizzle (conflict-free b64);
// coalesced smask fast path; defer-max rescale (THR=8).
__global__ __launch_bounds__(256,4) void attn_kernel(const ushort* __restrict__ Q, const ushort* __restrict__ Kv,
    const ushort* __restrict__ Vt, ushort* __restrict__ O, const int* __restrict__ smask, int causal){
  __shared__ ushort Ks[2][64 * 64];
  __shared__ ushort Vs[2][64 * 64];
  __shared__ __align__(16) char Ps[4][2048];
  const int p = blockIdx.x;
  const int x = p & 7, j = p >> 3;          // XCD, local 0..127
  const int gg = x * 8 + (j & 7);           // (b,head), co-located per XCD
  const int b = gg >> 4, head = gg & 15;
  const int rr = j >> 3;                    // 0..15
  int qt;
  if (causal){
    int lo = rr & 3, hi = rr >> 2;          // stride-4 class balance
    qt = (hi == 0) ? lo * 2 : (hi == 1) ? lo * 2 + 1 : (hi == 2) ? 15 - lo * 2 : 14 - lo * 2;
  } else qt = rr;
  const int t = threadIdx.x, lane = t & 63, wave = t >> 6;
  const int l15 = lane & 15, l4 = lane >> 4;
  const int qr0 = qt * 64 + wave * 16;
  const int sw = l15 << 3;                  // 4-bit slot swizzle: bijective, conflict-free b64

  bf16x8 aq[2];
#pragma unroll
  for (int kk = 0; kk < 2; ++kk)
    aq[kk] = *(const bf16x8*)(Q + (size_t)(b * 1024 + qr0 + l15) * 1024 + head * 64 + kk * 32 + l4 * 8);

  f32x4 cacc[4] = {};
  float mrow = -1e30f, lrow = 0.f;

  auto stage = [&](int buf, int k0){
#pragma unroll
    for (int jj = 0; jj < 2; ++jj){
      int cb = jj * 256 + wave * 64;
      int pp = cb + lane;
      int row = pp >> 3;
      int kc = (pp & 7) ^ (row & 7);
      const ushort* src = Kv + (size_t)(b * 1024 + k0 + row) * 1024 + head * 64 + kc * 8;
      __builtin_amdgcn_global_load_lds((GVOID*)src, (LVOID*)(&Ks[buf][cb * 8]), 16, 0, 0);
    }
#pragma unroll
    for (int jj = 0; jj < 2; ++jj){
      int cb = jj * 256 + wave * 64;
      int pp = cb + lane;
      int row = pp >> 3;
      int kc = (pp & 7) ^ (row & 7);
      const ushort* src = Vt + (size_t)((b * 16 + head) * 64 + row) * 1024 + k0 + kc * 8;
      __builtin_amdgcn_global_load_lds((GVOID*)src, (LVOID*)(&Vs[buf][cb * 8]), 16, 0, 0);
    }
  };

  const int nkt = causal ? (qt + 1) : 16;
  stage(0, 0);
  __syncthreads();
  char* Pb = &Ps[wave][0];
  for (int kt = 0; kt < nkt; ++kt){
    const int cur = kt & 1;
    const int k0 = kt * 64;
    if (kt + 1 < nkt) stage(cur ^ 1, (kt + 1) * 64);
    const ushort* Kb_ = &Ks[cur][0];
    const ushort* Vb_ = &Vs[cur][0];
    f32x4 st[4] = {};
#pragma unroll
    for (int kk = 0; kk < 2; ++kk){
      bf16x8 ak[4];
#pragma unroll
      for (int n = 0; n < 4; ++n){
        int row = n * 16 + l15;
        int ch = row * 8 + ((kk * 4 + l4) ^ (row & 7));
        ak[n] = *(const bf16x8*)(Kb_ + ch * 8);
      }
#pragma unroll
      for (int n = 0; n < 4; ++n)
        st[n] = __builtin_amdgcn_mfma_f32_16x16x32_bf16(ak[n], aq[kk], st[n], 0, 0, 0);
    }
    if (causal && k0 + 63 > qr0){
#pragma unroll
      for (int n = 0; n < 4; ++n)
#pragma unroll
      for (int r = 0; r < 4; ++r)
        if (k0 + n * 16 + l4 * 4 + r > qr0 + l15) st[n][r] = -1.5e6f;
    }
    if (smask){
      int myv = smask[b * 1024 + k0 + lane];          // one coalesced load per wave
      if (!__all(myv != 0)){
#pragma unroll
        for (int n = 0; n < 4; ++n)
#pragma unroll
        for (int r = 0; r < 4; ++r){
          int mv = smask[b * 1024 + k0 + n * 16 + l4 * 4 + r];
          if (mv == 0) st[n][r] = -1.5e6f;
        }
      }
    }
    float mx = st[0][0];
#pragma unroll
    for (int n = 0; n < 4; ++n)
#pragma unroll
    for (int r = 0; r < 4; ++r) mx = fmaxf(mx, st[n][r]);
    mx = fmaxf(mx, __shfl_xor(mx, 16));
    mx = fmaxf(mx, __shfl_xor(mx, 32));
    if (!__all(mx <= mrow + 8.f)){
      float mn = fmaxf(mrow, mx);
      float scal = __builtin_amdgcn_exp2f(mrow - mn);
      mrow = mn;
      lrow *= scal;
#pragma unroll
      for (int r = 0; r < 4; ++r){
        float sb = __shfl(scal, l4 * 4 + r);
#pragma unroll
        for (int nd = 0; nd < 4; ++nd) cacc[nd][r] *= sb;
      }
    }
    float ps = 0.f;
#pragma unroll
    for (int n = 0; n < 4; ++n)
#pragma unroll
    for (int r = 0; r < 4; ++r){
      float pv = __builtin_amdgcn_exp2f(st[n][r] - mrow);
      st[n][r] = pv;
      ps += pv;
    }
    ps += __shfl_xor(ps, 16);
    ps += __shfl_xor(ps, 32);
    lrow += ps;
#pragma unroll
    for (int n = 0; n < 4; ++n){
      unsigned lo_, hi_;
      asm("v_cvt_pk_bf16_f32 %0, %1, %2" : "=v"(lo_) : "v"(st[n][0]), "v"(st[n][1]));
      asm("v_cvt_pk_bf16_f32 %0, %1, %2" : "=v"(hi_) : "v"(st[n][2]), "v"(st[n][3]));
      unsigned long long pk = (unsigned long long)lo_ | ((unsigned long long)hi_ << 32);
      *(unsigned long long*)(Pb + l15 * 128 + ((n * 32 + l4 * 8) ^ sw)) = pk;
    }
#pragma unroll
    for (int ks = 0; ks < 2; ++ks){
      bf16x8 bv[4];
#pragma unroll
      for (int nd = 0; nd < 4; ++nd){
        int row = nd * 16 + l15;
        int ch = row * 8 + ((ks * 4 + l4) ^ (row & 7));
        bv[nd] = *(const bf16x8*)(Vb_ + ch * 8);
      }
      int base = l15 * 128;
      int o = ks * 64 + l4 * 16;
      union { bf16x8 v; unsigned long long u[2]; } pa;
      pa.u[0] = *(const unsigned long long*)(Pb + base + ((o    ) ^ sw));
      pa.u[1] = *(const unsigned long long*)(Pb + base + ((o + 8) ^ sw));
#pragma unroll
      for (int nd = 0; nd < 4; ++nd)
        cacc[nd] = __builtin_amdgcn_mfma_f32_16x16x32_bf16(pa.v, bv[nd], cacc[nd], 0, 0, 0);
    }
    __syncthreads();
  }
#pragma unroll
  for (int r = 0; r < 4; ++r){
    float lb = __shfl(lrow, l4 * 4 + r);
    float inv = 1.f / lb;
    int row = qr0 + l4 * 4 + r;
#pragma unroll
    for (int nd = 0; nd < 4; ++nd){
      int col = head * 64 + nd * 16 + l15;
      O[(size_t)(b * 1024 + row) * 1024 + col] = f2bf(cacc[nd][r] * inv);
    }
  }
}

// ---------------- LayerNorm over H=1024 ----------------
__global__ __launch_bounds__(256) void ln_kernel(const ushort* __restrict__ X, const float* __restrict__ g,
    const float* __restrict__ bta, ushort* __restrict__ outb, float* __restrict__ outf){
  const int row = blockIdx.x, t = threadIdx.x;
  const ushort* xr = X + (size_t)row * 1024;
  ushort4 u = *(const ushort4*)(xr + t * 4);
  float x0 = bf2f(u.x), x1 = bf2f(u.y), x2 = bf2f(u.z), x3 = bf2f(u.w);
  float s = x0 + x1 + x2 + x3;
  float s2 = x0 * x0 + x1 * x1 + x2 * x2 + x3 * x3;
#pragma unroll
  for (int d = 1; d < 64; d <<= 1){ s += __shfl_xor(s, d); s2 += __shfl_xor(s2, d); }
  __shared__ float red[8];
  const int lane = t & 63, wave = t >> 6;
  if (lane == 0){ red[wave] = s; red[4 + wave] = s2; }
  __syncthreads();
  s = red[0] + red[1] + red[2] + red[3];
  s2 = red[4] + red[5] + red[6] + red[7];
  float mu = s * (1.f / 1024.f);
  float var = fmaxf(s2 * (1.f / 1024.f) - mu * mu, 0.f);
  float rstd = rsqrtf(var + 1e-12f);
  int col = t * 4;
  float y0 = (x0 - mu) * rstd * g[col + 0] + bta[col + 0];
  float y1 = (x1 - mu) * rstd * g[col + 1] + bta[col + 1];
  float y2 = (x2 - mu) * rstd * g[col + 2] + bta[col + 2];
  float y3 = (x3 - mu) * rstd * g[col + 3] + bta[col + 3];
  if (outb){
    ushort4 o; o.x = f2bf(y0); o.y = f2bf(y1); o.z = f2bf(y2); o.w = f2bf(y3);
    *(ushort4*)(outb + (size_t)row * 1024 + col) = o;
  } else {
    float4 o; o.x = y0; o.y = y1; o.z = y2; o.w = y3;
    *(float4*)(outf + (size_t)row * 1024 + col) = o;
  }
}

extern "C" void kernel_launch(void* const* d_in, const int* in_sizes, int n_in,
                              void* d_out, int out_size, void* d_ws, size_t ws_size,
                              hipStream_t stream){
  const float* enc = (const float*)d_in[0];
  const float* dec = (const float*)d_in[1];
  const int* smask = (const int*)d_in[2];
  const float* q_w  = (const float*)d_in[4];  const float* q_b  = (const float*)d_in[5];
  const float* k_w  = (const float*)d_in[6];  const float* k_b  = (const float*)d_in[7];
  const float* v_w  = (const float*)d_in[8];  const float* v_b  = (const float*)d_in[9];
  const float* sq_w = (const float*)d_in[10]; const float* sq_b = (const float*)d_in[11];
  const float* sk_w = (const float*)d_in[12]; const float* sk_b = (const float*)d_in[13];
  const float* sv_w = (const float*)d_in[14]; const float* sv_b = (const float*)d_in[15];
  const float* dw   = (const float*)d_in[16]; const float* db   = (const float*)d_in[17];
  const float* lng  = (const float*)d_in[18]; const float* lnb  = (const float*)d_in[19];
  ushort* ws = (ushort*)d_ws;
  const size_t MEG = 1024u * 1024u;
  ushort* decb = ws + 0 * MEG;
  ushort* encb = ws + 4 * MEG;
  ushort* Qb   = ws + 8 * MEG;
  ushort* Kb   = ws + 12 * MEG;
  ushort* Vtb  = ws + 20 * MEG;
  ushort* ctx  = ws + 24 * MEG;
  ushort* S1   = ws + 28 * MEG;
  ushort* Wq  = ws + 32 * MEG; ushort* Wk  = ws + 33 * MEG; ushort* Wv  = ws + 34 * MEG;
  ushort* Wsq = ws + 35 * MEG; ushort* Wsk = ws + 36 * MEG; ushort* Wsv = ws + 37 * MEG;
  ushort* Wd  = ws + 38 * MEG;
  const int M = 4096, N = 1024, Kd = 1024;
  {
    CvtArgs ca;
    ca.s[0] = dec;  ca.d[0] = decb; ca.blks[0] = 4096;
    ca.s[1] = enc;  ca.d[1] = encb; ca.blks[1] = 4096;
    ca.s[2] = q_w;  ca.d[2] = Wq;   ca.blks[2] = 1024;
    ca.s[3] = k_w;  ca.d[3] = Wk;   ca.blks[3] = 1024;
    ca.s[4] = v_w;  ca.d[4] = Wv;   ca.blks[4] = 1024;
    ca.s[5] = sq_w; ca.d[5] = Wsq;  ca.blks[5] = 1024;
    ca.s[6] = sk_w; ca.d[6] = Wsk;  ca.blks[6] = 1024;
    ca.s[7] = sv_w; ca.d[7] = Wsv;  ca.blks[7] = 1024;
    ca.s[8] = dw;   ca.d[8] = Wd;   ca.blks[8] = 1024;
    cvtk_multi<<<15360, 256, 0, stream>>>(ca);
  }
  // ---- self attention ----
  {
    GemmArgs ga = {};
    ga.A[0] = decb; ga.A[1] = decb; ga.A[2] = decb;
    ga.W[0] = Wq;   ga.W[1] = Wk;   ga.W[2] = Wv;
    ga.bias[0] = q_b; ga.bias[1] = k_b; ga.bias[2] = v_b;
    ga.C[0] = Qb;   ga.C[1] = Kb;   ga.C[2] = Vtb;
    ga.mode[0] = 0; ga.mode[1] = 0; ga.mode[2] = 2;
    ga.scale[0] = LOG2E; ga.scale[1] = 1.f; ga.scale[2] = 1.f;
    gemm128<<<768, 256, 0, stream>>>(ga, 3, N, Kd);
  }
  attn_kernel<<<1024, 256, 0, stream>>>(Qb, Kb, Vtb, ctx, nullptr, 1);
  {
    GemmArgs ga = {};
    ga.A[0] = ctx; ga.W[0] = Wd; ga.bias[0] = db; ga.R[0] = Qb; ga.C[0] = S1; ga.mode[0] = 1;
    ga.scale[0] = 1.f;
    gemm_bt<<<512, 256, 0, stream>>>(ga, 1, M, N, Kd);
  }
  ln_kernel<<<4096, 256, 0, stream>>>(S1, lng, lnb, decb, nullptr);
  // ---- cross attention ----
  {
    GemmArgs ga = {};
    ga.A[0] = decb; ga.A[1] = encb; ga.A[2] = encb;
    ga.W[0] = Wsq;  ga.W[1] = Wsk;  ga.W[2] = Wsv;
    ga.bias[0] = sq_b; ga.bias[1] = sk_b; ga.bias[2] = sv_b;
    ga.C[0] = Qb;   ga.C[1] = Kb;   ga.C[2] = Vtb;
    ga.mode[0] = 0; ga.mode[1] = 0; ga.mode[2] = 2;
    ga.scale[0] = LOG2E; ga.scale[1] = 1.f; ga.scale[2] = 1.f;
    gemm128<<<768, 256, 0, stream>>>(ga, 3, N, Kd);
  }
  attn_kernel<<<1024, 256, 0, stream>>>(Qb, Kb, Vtb, ctx, smask, 0);
  {
    GemmArgs ga = {};
    ga.A[0] = ctx; ga.W[0] = Wd; ga.bias[0] = db; ga.R[0] = Qb; ga.C[0] = S1; ga.mode[0] = 1;
    ga.scale[0] = 1.f;
    gemm_bt<<<512, 256, 0, stream>>>(ga, 1, M, N, Kd);
  }
  ln_kernel<<<4096, 256, 0, stream>>>(S1, lng, lnb, nullptr, (float*)d_out);
}